// Round 1
// baseline (1404.292 us; speedup 1.0000x reference)
//
#include <hip/hip_runtime.h>
#include <hip/hip_bf16.h>

#define NB 65536
#define NL 8

typedef __bf16 v8bf __attribute__((ext_vector_type(8)));
typedef __bf16 v4bf __attribute__((ext_vector_type(4)));
typedef float  v4f  __attribute__((ext_vector_type(4)));
typedef unsigned int uint32;
typedef uint32 v4u __attribute__((ext_vector_type(4)));

// ---------------------------------------------------------------------------
// prep: W[l][m] (256x256 f32, [k][n]) -> bf16 transposed [l*4+m][n][k] in ws
// m order matches main-loop chunk stream: 0=Ws1, 1=Ws2, 2=Wt1, 3=Wt2
// ---------------------------------------------------------------------------
__global__ void prep_weights(const float* __restrict__ W1s, const float* __restrict__ W2s,
                             const float* __restrict__ W1t, const float* __restrict__ W2t,
                             __hip_bfloat16* __restrict__ o) {
    const int col = blockIdx.x & 255;          // output column n
    const int lm  = blockIdx.x >> 8;           // layer*4 + m  (0..31)
    const int l = lm >> 2, m = lm & 3;
    const float* s = (m == 0 ? W1s : m == 1 ? W2s : m == 2 ? W1t : W2t) + l * 65536;
    const int k = threadIdx.x;
    o[((size_t)lm * 256 + col) * 256 + k] = __float2bfloat16(s[k * 256 + col]);
}

// ---------------------------------------------------------------------------
// fused RealNVP: u = z evens (invariant, reg-resident bf16 frags)
//                v = z odds  (f32 regs, C/D layout), 8 layers fused
// swapped-operand MFMA: D = W^T (A) x act^T (B)  -> D[m=outcol][n=batchrow]
// ---------------------------------------------------------------------------
#define MFMA16(a, b, c) __builtin_amdgcn_mfma_f32_16x16x32_bf16((a), (b), (c), 0, 0, 0)

static __device__ __forceinline__ float fast_rcp(float x) {
#if __has_builtin(__builtin_amdgcn_rcpf)
    return __builtin_amdgcn_rcpf(x);
#else
    return 1.0f / x;
#endif
}

__launch_bounds__(256, 2)
__global__ void realnvp_fused(const float* __restrict__ z,
                              const float* __restrict__ bs1, const float* __restrict__ bs2,
                              const float* __restrict__ bt1, const float* __restrict__ bt2,
                              const __hip_bfloat16* __restrict__ WT,
                              float* __restrict__ out) {
    extern __shared__ char smem[];   // [0,16K): W chunk buf; [16K+w*16K, +16K): per-wave hidden
    const int tid  = threadIdx.x;
    const int lane = tid & 63;
    const int wv   = tid >> 6;
    const int q  = lane & 15;        // n index (batch row within 16-tile / LDS row low bits)
    const int g  = lane >> 4;        // quad group
    const int l7 = lane & 7;
    const int rowbase = blockIdx.x * 128 + wv * 32;

    // fragment-read LDS byte offsets (same pattern for Wbuf cols and hidden rows):
    // row q, kbyte = kt*64 + g*16, XOR-swizzled by (row&7)<<4  [T2]
    int off[8];
#pragma unroll
    for (int kt = 0; kt < 8; ++kt)
        off[kt] = q * 512 + ((kt * 64 + g * 16) ^ (l7 << 4));
    const int hb = 16384 + wv * 16384;

    // weight staging: thread covers 64B of the 16KB chunk (linear global -> swizzled LDS)
    const int wcol = tid >> 3, wj = tid & 7;
    int wraddr[4];
#pragma unroll
    for (int i = 0; i < 4; ++i)
        wraddr[i] = wcol * 512 + ((wj * 64 + i * 16) ^ ((wcol & 7) << 4));

    // ---------------- prologue: load u (even cols -> bf16 B-frags) and v (odd cols -> f32)
    v8bf u[2][8];
    v4f  v[2][16];
#pragma unroll
    for (int bt = 0; bt < 2; ++bt) {
        const char* zr = (const char*)z + (size_t)(rowbase + bt * 16 + q) * 2048;
#pragma unroll
        for (int kt = 0; kt < 8; ++kt) {
            const v4f* p = (const v4f*)(zr + kt * 256 + g * 64);
            v4f f0 = p[0], f1 = p[1], f2 = p[2], f3 = p[3];
            v8bf t;
            t[0] = (__bf16)f0.x; t[1] = (__bf16)f0.z;
            t[2] = (__bf16)f1.x; t[3] = (__bf16)f1.z;
            t[4] = (__bf16)f2.x; t[5] = (__bf16)f2.z;
            t[6] = (__bf16)f3.x; t[7] = (__bf16)f3.z;
            u[bt][kt] = t;
        }
#pragma unroll
        for (int ht = 0; ht < 16; ++ht) {
            const v4f* p = (const v4f*)(zr + ht * 128 + g * 32);
            v4f f0 = p[0], f1 = p[1];
            v4f t; t.x = f0.y; t.y = f0.w; t.z = f1.y; t.w = f1.w;
            v[bt][ht] = t;
        }
    }

    float lj0 = 0.0f, lj1 = 0.0f;

    // ---------------- weight chunk staging (reg double-buffer, T14 issue-early/write-late)
    v4u wreg[4];
    const char* WTb = (const char*)WT;
#pragma unroll
    for (int i = 0; i < 4; ++i)
        wreg[i] = ((const v4u*)(WTb + (size_t)tid * 64))[i];          // chunk 0
#pragma unroll
    for (int i = 0; i < 4; ++i)
        *(v4u*)(smem + wraddr[i]) = wreg[i];
#pragma unroll
    for (int i = 0; i < 4; ++i)
        wreg[i] = ((const v4u*)(WTb + 16384 + (size_t)tid * 64))[i];  // chunk 1
    __syncthreads();                                                  // Wbuf = chunk 0 ready

    int nextc = 2;
    auto advance = [&]() {
        __syncthreads();                        // all waves done reading Wbuf
#pragma unroll
        for (int i = 0; i < 4; ++i)
            *(v4u*)(smem + wraddr[i]) = wreg[i];
        if (nextc < 256) {
            const char* p = WTb + (size_t)nextc * 16384 + (size_t)tid * 64;
#pragma unroll
            for (int i = 0; i < 4; ++i)
                wreg[i] = ((const v4u*)p)[i];   // in flight across next grp's compute
        }
        ++nextc;
        __syncthreads();                        // Wbuf = next chunk ready
    };

    // G1: hidden = relu(u @ W1 + b1)  -> per-wave-private swizzled LDS (bf16)
    auto g1 = [&](const float* bias) {
#pragma unroll
        for (int grp = 0; grp < 8; ++grp) {
            v4f acc[2][2] = {};
#pragma unroll
            for (int kt = 0; kt < 8; ++kt) {
                v8bf a0 = *(const v8bf*)(smem + off[kt]);
                v8bf a1 = *(const v8bf*)(smem + off[kt] + 8192);
                acc[0][0] = MFMA16(a0, u[0][kt], acc[0][0]);
                acc[0][1] = MFMA16(a0, u[1][kt], acc[0][1]);
                acc[1][0] = MFMA16(a1, u[0][kt], acc[1][0]);
                acc[1][1] = MFMA16(a1, u[1][kt], acc[1][1]);
            }
#pragma unroll
            for (int mt = 0; mt < 2; ++mt) {
                v4f b4 = *(const v4f*)(bias + grp * 32 + mt * 16 + g * 4);
#pragma unroll
                for (int bt = 0; bt < 2; ++bt) {
                    const int b = bt * 16 + q;
                    v4bf hv;
#pragma unroll
                    for (int e = 0; e < 4; ++e)
                        hv[e] = (__bf16)fmaxf(acc[mt][bt][e] + b4[e], 0.0f);
                    // lane holds 4 contiguous h-cols -> single b64 write
                    *(v4bf*)(smem + hb + b * 512 +
                             ((grp * 64 + mt * 32 + g * 8) ^ ((b & 7) << 4))) = hv;
                }
            }
            advance();
        }
    };

    // G2: o = hidden @ W2 + b2 ; s-path: s=tanh(o), lj+=s, v*=exp(s) ; t-path: v+=o
    auto g2 = [&](const float* bias, bool spath) {
#pragma unroll
        for (int grp = 0; grp < 8; ++grp) {
            v4f acc[2][2] = {};
#pragma unroll
            for (int kt = 0; kt < 8; ++kt) {
                v8bf a0 = *(const v8bf*)(smem + off[kt]);
                v8bf a1 = *(const v8bf*)(smem + off[kt] + 8192);
                v8bf h0 = *(const v8bf*)(smem + hb + off[kt]);
                v8bf h1 = *(const v8bf*)(smem + hb + off[kt] + 8192);
                acc[0][0] = MFMA16(a0, h0, acc[0][0]);
                acc[0][1] = MFMA16(a0, h1, acc[0][1]);
                acc[1][0] = MFMA16(a1, h0, acc[1][0]);
                acc[1][1] = MFMA16(a1, h1, acc[1][1]);
            }
#pragma unroll
            for (int mt = 0; mt < 2; ++mt) {
                v4f b4 = *(const v4f*)(bias + grp * 32 + mt * 16 + g * 4);
#pragma unroll
                for (int bt = 0; bt < 2; ++bt) {
                    v4f sv = acc[mt][bt];
#pragma unroll
                    for (int e = 0; e < 4; ++e) sv[e] += b4[e];
                    if (spath) {
#pragma unroll
                        for (int e = 0; e < 4; ++e) {
                            float e2 = __expf(2.0f * sv[e]);
                            float s  = 1.0f - 2.0f * fast_rcp(e2 + 1.0f);   // tanh
                            if (bt == 0) lj0 += s; else lj1 += s;
                            v[bt][grp * 2 + mt][e] *= __expf(s);
                        }
                    } else {
#pragma unroll
                        for (int e = 0; e < 4; ++e)
                            v[bt][grp * 2 + mt][e] += sv[e];
                    }
                }
            }
            advance();
        }
    };

#pragma unroll 1
    for (int layer = 0; layer < NL; ++layer) {
        g1(bs1 + layer * 256);
        g2(bs2 + layer * 256, true);
        g1(bt1 + layer * 256);
        g2(bt2 + layer * 256, false);
    }

    // ---------------- epilogue
    float* ob = out + (size_t)rowbase * 512;
#pragma unroll
    for (int bt = 0; bt < 2; ++bt) {
        float* orp = ob + (size_t)(bt * 16 + q) * 512;
#pragma unroll
        for (int ht = 0; ht < 16; ++ht)
            *(v4f*)(orp + 256 + ht * 16 + g * 4) = v[bt][ht];     // out[:,256:] = v
#pragma unroll
        for (int kt = 0; kt < 8; ++kt) {                          // out[:,:256] = u (evens)
            v4f lo, hi;
            lo.x = (float)u[bt][kt][0]; lo.y = (float)u[bt][kt][1];
            lo.z = (float)u[bt][kt][2]; lo.w = (float)u[bt][kt][3];
            hi.x = (float)u[bt][kt][4]; hi.y = (float)u[bt][kt][5];
            hi.z = (float)u[bt][kt][6]; hi.w = (float)u[bt][kt][7];
            *(v4f*)(orp + kt * 32 + g * 8)     = lo;
            *(v4f*)(orp + kt * 32 + g * 8 + 4) = hi;
        }
    }
    // logjac: reduce the 4 g-groups (lanes q, q+16, q+32, q+48)
    lj0 += __shfl_xor(lj0, 16); lj0 += __shfl_xor(lj0, 32);
    lj1 += __shfl_xor(lj1, 16); lj1 += __shfl_xor(lj1, 32);
    if (lane < 16) {
        out[(size_t)NB * 512 + rowbase + lane]      = lj0;
        out[(size_t)NB * 512 + rowbase + 16 + lane] = lj1;
    }
}

// ---------------------------------------------------------------------------
extern "C" void kernel_launch(void* const* d_in, const int* in_sizes, int n_in,
                              void* d_out, int out_size, void* d_ws, size_t ws_size,
                              hipStream_t stream) {
    (void)in_sizes; (void)n_in; (void)out_size; (void)ws_size;
    const float* z   = (const float*)d_in[0];
    const float* Ws1 = (const float*)d_in[1];
    const float* bs1 = (const float*)d_in[2];
    const float* Ws2 = (const float*)d_in[3];
    const float* bs2 = (const float*)d_in[4];
    const float* Wt1 = (const float*)d_in[5];
    const float* bt1 = (const float*)d_in[6];
    const float* Wt2 = (const float*)d_in[7];
    const float* bt2 = (const float*)d_in[8];
    __hip_bfloat16* WT = (__hip_bfloat16*)d_ws;   // 4 MB bf16 transposed weights
    float* out = (float*)d_out;

    prep_weights<<<dim3(8192), dim3(256), 0, stream>>>(Ws1, Ws2, Wt1, Wt2, WT);

    hipFuncSetAttribute(reinterpret_cast<const void*>(realnvp_fused),
                        hipFuncAttributeMaxDynamicSharedMemorySize, 81920);
    realnvp_fused<<<dim3(512), dim3(256), 81920, stream>>>(z, bs1, bs2, bt1, bt2, WT, out);
}

// Round 2
// 1070.779 us; speedup vs baseline: 1.3115x; 1.3115x over previous
//
#include <hip/hip_runtime.h>
#include <hip/hip_bf16.h>

#define NB 65536
#define NL 8

typedef __bf16 v8bf __attribute__((ext_vector_type(8)));
typedef __bf16 v4bf __attribute__((ext_vector_type(4)));
typedef float  v4f  __attribute__((ext_vector_type(4)));
typedef unsigned int uint32;
typedef uint32 v4u __attribute__((ext_vector_type(4)));

// ---------------------------------------------------------------------------
// prep: W[l][m] (256x256 f32, [k][n]) -> bf16 W^T [lm][col][k'] in ws, with
// k' = k ^ ((col&7)<<3): in-chunk XOR pre-swizzle (16B granules) so the main
// kernel's LDS staging is LINEAR (conflict-free) and fragment READS apply the
// same XOR (m173 pattern). m order matches stream: 0=Ws1,1=Ws2,2=Wt1,3=Wt2.
// ---------------------------------------------------------------------------
__global__ void prep_weights(const float* __restrict__ W1s, const float* __restrict__ W2s,
                             const float* __restrict__ W1t, const float* __restrict__ W2t,
                             __hip_bfloat16* __restrict__ o) {
    const int col = blockIdx.x & 255;          // output column n
    const int lm  = blockIdx.x >> 8;           // layer*4 + m  (0..31)
    const int l = lm >> 2, m = lm & 3;
    const float* s = (m == 0 ? W1s : m == 1 ? W2s : m == 2 ? W1t : W2t) + l * 65536;
    const int k  = threadIdx.x;
    const int kp = k ^ ((col & 7) << 3);       // element-index swizzle
    o[((size_t)lm * 256 + col) * 256 + kp] = __float2bfloat16(s[k * 256 + col]);
}

// ---------------------------------------------------------------------------
// fused RealNVP: u = z evens (invariant, reg-resident bf16 B-frags)
//                v = z odds  (f32 regs, C/D layout), 8 layers fused
// 16 batch rows per wave (spill-free), 8 waves/block = 128 rows/block.
// swapped-operand MFMA: D = W^T (A) x act^T (B)  -> D[m=outcol][n=batchrow]
// ---------------------------------------------------------------------------
#define MFMA16(a, b, c) __builtin_amdgcn_mfma_f32_16x16x32_bf16((a), (b), (c), 0, 0, 0)

static __device__ __forceinline__ float fast_rcp(float x) {
#if __has_builtin(__builtin_amdgcn_rcpf)
    return __builtin_amdgcn_rcpf(x);
#else
    return 1.0f / x;
#endif
}

__launch_bounds__(512, 2)
__global__ void realnvp_fused(const float* __restrict__ z,
                              const float* __restrict__ bs1, const float* __restrict__ bs2,
                              const float* __restrict__ bt1, const float* __restrict__ bt2,
                              const __hip_bfloat16* __restrict__ WT,
                              float* __restrict__ out) {
    extern __shared__ char smem[];   // [0,16K): W chunk; [16K + wv*8K, +8K): per-wave hidden
    const int tid  = threadIdx.x;
    const int lane = tid & 63;
    const int wv   = tid >> 6;       // 0..7
    const int q  = lane & 15;        // batch row within wave / LDS row
    const int g  = lane >> 4;        // quad group
    const int rowbase = blockIdx.x * 128 + wv * 16;

    // fragment-read LDS byte offsets (W chunk rows AND hidden rows share this):
    // row q, kbyte = kt*64 + g*16, XOR ((row&7)<<4)  [T2; content pre-swizzled for W]
    int off[8];
#pragma unroll
    for (int kt = 0; kt < 8; ++kt)
        off[kt] = q * 512 + ((kt * 64 + g * 16) ^ ((q & 7) << 4));
    const int hb = 16384 + wv * 8192;

    // ---------------- prologue: u (even cols -> bf16 B-frags), v (odd cols -> f32 C/D)
    v8bf u[8];
    v4f  v[16];
    {
        const char* zr = (const char*)z + (size_t)(rowbase + q) * 2048;
#pragma unroll
        for (int kt = 0; kt < 8; ++kt) {
            const v4f* p = (const v4f*)(zr + kt * 256 + g * 64);
            v4f f0 = p[0], f1 = p[1], f2 = p[2], f3 = p[3];
            v8bf t;
            t[0] = (__bf16)f0.x; t[1] = (__bf16)f0.z;
            t[2] = (__bf16)f1.x; t[3] = (__bf16)f1.z;
            t[4] = (__bf16)f2.x; t[5] = (__bf16)f2.z;
            t[6] = (__bf16)f3.x; t[7] = (__bf16)f3.z;
            u[kt] = t;
        }
#pragma unroll
        for (int ht = 0; ht < 16; ++ht) {
            const v4f* p = (const v4f*)(zr + ht * 128 + g * 32);
            v4f f0 = p[0], f1 = p[1];
            v4f t; t.x = f0.y; t.y = f0.w; t.z = f1.y; t.w = f1.w;
            v[ht] = t;
        }
    }

    float lj = 0.0f;

    // ---------------- weight staging: linear LDS (pre-swizzled content), reg dbuf (T14)
    v4u wreg[2];
    const char* WTb = (const char*)WT;
    auto loadregs = [&](int c) {
        const char* p = WTb + (size_t)c * 16384 + (size_t)tid * 16;
        wreg[0] = *(const v4u*)p;
        wreg[1] = *(const v4u*)(p + 8192);
    };
    loadregs(0);
    *(v4u*)(smem + tid * 16)        = wreg[0];
    *(v4u*)(smem + 8192 + tid * 16) = wreg[1];
    loadregs(1);
    __syncthreads();                 // chunk 0 ready in LDS, chunk 1 in regs

    int nextc = 2;
    auto advance = [&]() {
        __syncthreads();             // all waves done reading current chunk
        *(v4u*)(smem + tid * 16)        = wreg[0];
        *(v4u*)(smem + 8192 + tid * 16) = wreg[1];
        if (nextc < 256) loadregs(nextc);   // in flight across next grp's compute
        ++nextc;
        __syncthreads();             // next chunk ready
    };

    // G1: hidden = relu(u @ W1 + b1) -> per-wave-private swizzled LDS (bf16)
    auto g1 = [&](const float* bias) {
#pragma unroll
        for (int grp = 0; grp < 8; ++grp) {
            v4f acc0 = {}, acc1 = {};
#pragma unroll
            for (int kt = 0; kt < 8; ++kt) {
                v8bf a0 = *(const v8bf*)(smem + off[kt]);
                v8bf a1 = *(const v8bf*)(smem + off[kt] + 8192);
                acc0 = MFMA16(a0, u[kt], acc0);
                acc1 = MFMA16(a1, u[kt], acc1);
            }
#pragma unroll
            for (int mt = 0; mt < 2; ++mt) {
                v4f a  = mt ? acc1 : acc0;
                v4f b4 = *(const v4f*)(bias + grp * 32 + mt * 16 + g * 4);
                v4bf hv;
#pragma unroll
                for (int e = 0; e < 4; ++e)
                    hv[e] = (__bf16)fmaxf(a[e] + b4[e], 0.0f);
                // lane holds 4 contiguous h-cols -> single b64 write
                *(v4bf*)(smem + hb + q * 512 +
                         ((grp * 64 + mt * 32 + g * 8) ^ ((q & 7) << 4))) = hv;
            }
            advance();
        }
    };

    // G2: o = hidden @ W2 + b2 ; s: s=tanh(o), lj+=s, v*=exp(s) ; t: v+=o
    auto g2 = [&](const float* bias, bool spath) {
#pragma unroll
        for (int grp = 0; grp < 8; ++grp) {
            v4f acc0 = {}, acc1 = {};
#pragma unroll
            for (int kt = 0; kt < 8; ++kt) {
                v8bf a0 = *(const v8bf*)(smem + off[kt]);
                v8bf a1 = *(const v8bf*)(smem + off[kt] + 8192);
                v8bf h0 = *(const v8bf*)(smem + hb + off[kt]);
                acc0 = MFMA16(a0, h0, acc0);
                acc1 = MFMA16(a1, h0, acc1);
            }
#pragma unroll
            for (int mt = 0; mt < 2; ++mt) {
                v4f sv = mt ? acc1 : acc0;
                v4f b4 = *(const v4f*)(bias + grp * 32 + mt * 16 + g * 4);
#pragma unroll
                for (int e = 0; e < 4; ++e) sv[e] += b4[e];
                if (spath) {
#pragma unroll
                    for (int e = 0; e < 4; ++e) {
                        float e2 = __expf(2.0f * sv[e]);
                        float s  = 1.0f - 2.0f * fast_rcp(e2 + 1.0f);   // tanh
                        lj += s;
                        v[grp * 2 + mt][e] *= __expf(s);
                    }
                } else {
#pragma unroll
                    for (int e = 0; e < 4; ++e)
                        v[grp * 2 + mt][e] += sv[e];
                }
            }
            advance();
        }
    };

#pragma unroll 1
    for (int layer = 0; layer < NL; ++layer) {
        g1(bs1 + layer * 256);
        g2(bs2 + layer * 256, true);
        g1(bt1 + layer * 256);
        g2(bt2 + layer * 256, false);
    }

    // ---------------- epilogue
    {
        float* orp = out + (size_t)(rowbase + q) * 512;
#pragma unroll
        for (int ht = 0; ht < 16; ++ht)
            *(v4f*)(orp + 256 + ht * 16 + g * 4) = v[ht];         // out[:,256:] = v
#pragma unroll
        for (int kt = 0; kt < 8; ++kt) {                          // out[:,:256] = u
            v4f lo, hi;
            lo.x = (float)u[kt][0]; lo.y = (float)u[kt][1];
            lo.z = (float)u[kt][2]; lo.w = (float)u[kt][3];
            hi.x = (float)u[kt][4]; hi.y = (float)u[kt][5];
            hi.z = (float)u[kt][6]; hi.w = (float)u[kt][7];
            *(v4f*)(orp + kt * 32 + g * 8)     = lo;
            *(v4f*)(orp + kt * 32 + g * 8 + 4) = hi;
        }
    }
    // logjac: reduce 4 g-groups (lanes q, q+16, q+32, q+48)
    lj += __shfl_xor(lj, 16);
    lj += __shfl_xor(lj, 32);
    if (lane < 16)
        out[(size_t)NB * 512 + rowbase + lane] = lj;
}

// ---------------------------------------------------------------------------
extern "C" void kernel_launch(void* const* d_in, const int* in_sizes, int n_in,
                              void* d_out, int out_size, void* d_ws, size_t ws_size,
                              hipStream_t stream) {
    (void)in_sizes; (void)n_in; (void)out_size; (void)ws_size;
    const float* z   = (const float*)d_in[0];
    const float* Ws1 = (const float*)d_in[1];
    const float* bs1 = (const float*)d_in[2];
    const float* Ws2 = (const float*)d_in[3];
    const float* bs2 = (const float*)d_in[4];
    const float* Wt1 = (const float*)d_in[5];
    const float* bt1 = (const float*)d_in[6];
    const float* Wt2 = (const float*)d_in[7];
    const float* bt2 = (const float*)d_in[8];
    __hip_bfloat16* WT = (__hip_bfloat16*)d_ws;   // 4 MB bf16 pre-swizzled weights
    float* out = (float*)d_out;

    prep_weights<<<dim3(8192), dim3(256), 0, stream>>>(Ws1, Ws2, Wt1, Wt2, WT);

    hipFuncSetAttribute(reinterpret_cast<const void*>(realnvp_fused),
                        hipFuncAttributeMaxDynamicSharedMemorySize, 81920);
    realnvp_fused<<<dim3(512), dim3(512), 81920, stream>>>(z, bs1, bs2, bt1, bt2, WT, out);
}

// Round 4
// 794.044 us; speedup vs baseline: 1.7685x; 1.3485x over previous
//
#include <hip/hip_runtime.h>
#include <hip/hip_bf16.h>

#define NB 65536
#define NL 8

typedef __bf16 v8bf __attribute__((ext_vector_type(8)));
typedef __bf16 v4bf __attribute__((ext_vector_type(4)));
typedef float  v4f  __attribute__((ext_vector_type(4)));

// ---------------------------------------------------------------------------
// prep: W[l][m] (256x256 f32, [k][n]) -> bf16 W^T [lm][outcol][k] (canonical,
// NO swizzle: main kernel reads A-frags directly from global/L2).
// m order: 0=Ws1, 1=Ws2, 2=Wt1, 3=Wt2
// ---------------------------------------------------------------------------
__global__ void prep_weights(const float* __restrict__ W1s, const float* __restrict__ W2s,
                             const float* __restrict__ W1t, const float* __restrict__ W2t,
                             __hip_bfloat16* __restrict__ o) {
    const int col = blockIdx.x & 255;          // output column
    const int lm  = blockIdx.x >> 8;           // layer*4 + m  (0..31)
    const int l = lm >> 2, m = lm & 3;
    const float* s = (m == 0 ? W1s : m == 1 ? W2s : m == 2 ? W1t : W2t) + l * 65536;
    const int k = threadIdx.x;
    o[((size_t)lm * 256 + col) * 256 + k] = __float2bfloat16(s[k * 256 + col]);
}

// ---------------------------------------------------------------------------
// Col-split fused RealNVP.
//  block = 512 thr (8 waves), 128 batch rows. Wave w owns out-cols [w*32,w*32+32).
//  u (even z cols): block-shared LDS, bf16, XOR-swizzled rows  [64 KB]
//  h (hidden):      block-shared LDS, bf16, XOR-swizzled rows  [64 KB]
//  v (odd z cols):  f32 regs in C/D layout, per owning wave    [64 VGPR]
//  W: bf16 A-frags loaded DIRECT global->VGPR (L2-resident, 1x amplification)
//  MFMA: D = W^T(A) x act^T(B): D[m=outcol][n=row]; m=g*4+e, n=q (m89 layout)
// ---------------------------------------------------------------------------
#define MFMA16(a, b, c) __builtin_amdgcn_mfma_f32_16x16x32_bf16((a), (b), (c), 0, 0, 0)

#define LDS_U  0
#define LDS_H  65536
#define LDS_LJ 131072
#define LDS_SZ 135168

static __device__ __forceinline__ float fast_rcp(float x) {
#if __has_builtin(__builtin_amdgcn_rcpf)
    return __builtin_amdgcn_rcpf(x);
#else
    return 1.0f / x;
#endif
}

__launch_bounds__(512)
__global__ void realnvp_fused(const float* __restrict__ z,
                              const float* __restrict__ bs1, const float* __restrict__ bs2,
                              const float* __restrict__ bt1, const float* __restrict__ bt2,
                              const __hip_bfloat16* __restrict__ WT,
                              float* __restrict__ out) {
    extern __shared__ char smem[];
    const int tid  = threadIdx.x;
    const int lane = tid & 63;
    const int wv   = tid >> 6;       // 0..7
    const int q  = lane & 15;        // n index (batch row within 16-tile)
    const int g  = lane >> 4;        // quad group (m = g*4+e)
    const int rowbase = blockIdx.x * 128;
    const int wc = wv * 32;          // wave's out-col slice base

    // ---- prologue: fill u-buf (evens of z -> bf16, swizzled rows)
    {
        const int r = tid >> 2, qt = tid & 3;
        const char* zr = (const char*)z + (size_t)(rowbase + r) * 2048 + qt * 512;
        char* ub = smem + LDS_U + r * 512;
        const int swz = (r & 7) << 4;
#pragma unroll
        for (int j = 0; j < 8; ++j) {
            v4f f0 = *(const v4f*)(zr + j * 64);
            v4f f1 = *(const v4f*)(zr + j * 64 + 16);
            v4f f2 = *(const v4f*)(zr + j * 64 + 32);
            v4f f3 = *(const v4f*)(zr + j * 64 + 48);
            v8bf t;
            t[0] = (__bf16)f0.x; t[1] = (__bf16)f0.z;
            t[2] = (__bf16)f1.x; t[3] = (__bf16)f1.z;
            t[4] = (__bf16)f2.x; t[5] = (__bf16)f2.z;
            t[6] = (__bf16)f3.x; t[7] = (__bf16)f3.z;
            *(v8bf*)(ub + ((qt * 128 + j * 16) ^ swz)) = t;
        }
    }

    // ---- v0: odd z cols of this wave's slice, f32, C/D layout v[mt][rt]
    v4f v[2][8];
#pragma unroll
    for (int mt = 0; mt < 2; ++mt) {
        const size_t cboff = (size_t)(wc * 8 + mt * 128 + g * 32);   // byte of z col 2*(wc+mt*16+g*4)
#pragma unroll
        for (int rt = 0; rt < 8; ++rt) {
            const char* zr = (const char*)z + (size_t)(rowbase + rt * 16 + q) * 2048 + cboff;
            v4f f0 = *(const v4f*)zr, f1 = *(const v4f*)(zr + 16);
            v4f t; t.x = f0.y; t.y = f0.w; t.z = f1.y; t.w = f1.w;
            v[mt][rt] = t;
        }
    }
    __syncthreads();                 // u-buf ready

    // B-frag read offsets: row (rt*16+q), k-granule (kt*64+g*16) XOR ((q&7)<<4)
    int xk[8];
#pragma unroll
    for (int kt = 0; kt < 8; ++kt)
        xk[kt] = (kt * 64 + g * 16) ^ ((q & 7) << 4);
    const int rq512 = q * 512;
    const int hwoff = (wv * 64 + g * 8);          // h-write granule base (byte)

    float lj[8];
#pragma unroll
    for (int rt = 0; rt < 8; ++rt) lj[rt] = 0.0f;

    // ---- one pass: out[:, wc..wc+32) = src @ W + b (mode 0: ->relu->h,
    //      mode 1: s-path update of v/lj, mode 2: t-path add to v)
    auto pass = [&](const __hip_bfloat16* Wm, const float* bias, int mode) {
        v4f acc[2][8] = {};
        const char* Wb = (const char*)Wm;
        v4f b0 = *(const v4f*)(bias + wc + g * 4);
        v4f b1 = *(const v4f*)(bias + wc + 16 + g * 4);
        const char* src = smem + (mode == 0 ? LDS_U : LDS_H);
#pragma unroll
        for (int kt = 0; kt < 8; ++kt) {
            v8bf a0 = *(const v8bf*)(Wb + (size_t)((wc + q) * 512 + kt * 64 + g * 16));
            v8bf a1 = *(const v8bf*)(Wb + (size_t)((wc + 16 + q) * 512 + kt * 64 + g * 16));
#pragma unroll
            for (int rt = 0; rt < 8; ++rt) {
                v8bf b = *(const v8bf*)(src + rt * 8192 + rq512 + xk[kt]);
                acc[0][rt] = MFMA16(a0, b, acc[0][rt]);
                acc[1][rt] = MFMA16(a1, b, acc[1][rt]);
            }
        }
        if (mode == 0) {
            char* hb = smem + LDS_H + rq512;
            const int swz = (q & 7) << 4;
#pragma unroll
            for (int mt = 0; mt < 2; ++mt) {
                v4f bb = mt ? b1 : b0;
#pragma unroll
                for (int rt = 0; rt < 8; ++rt) {
                    v4bf hv;
#pragma unroll
                    for (int e = 0; e < 4; ++e)
                        hv[e] = (__bf16)fmaxf(acc[mt][rt][e] + bb[e], 0.0f);
                    *(v4bf*)(hb + rt * 8192 + ((hwoff + mt * 32) ^ swz)) = hv;
                }
            }
        } else if (mode == 1) {
#pragma unroll
            for (int mt = 0; mt < 2; ++mt) {
                v4f bb = mt ? b1 : b0;
#pragma unroll
                for (int rt = 0; rt < 8; ++rt) {
#pragma unroll
                    for (int e = 0; e < 4; ++e) {
                        float pre = acc[mt][rt][e] + bb[e];
                        float e2  = __expf(2.0f * pre);
                        float s   = 1.0f - 2.0f * fast_rcp(e2 + 1.0f);   // tanh
                        lj[rt] += s;
                        v[mt][rt][e] *= __expf(s);
                    }
                }
            }
        } else {
#pragma unroll
            for (int mt = 0; mt < 2; ++mt) {
                v4f bb = mt ? b1 : b0;
#pragma unroll
                for (int rt = 0; rt < 8; ++rt) {
#pragma unroll
                    for (int e = 0; e < 4; ++e)
                        v[mt][rt][e] += acc[mt][rt][e] + bb[e];
                }
            }
        }
    };

#pragma unroll 1
    for (int l = 0; l < NL; ++l) {
        const __hip_bfloat16* Wl = WT + (size_t)l * 4 * 65536;
        pass(Wl,             bs1 + l * 256, 0); __syncthreads();   // h = relu(u W1s + b)
        pass(Wl + 1 * 65536, bs2 + l * 256, 1); __syncthreads();   // s-path: v *= exp(s)
        pass(Wl + 2 * 65536, bt1 + l * 256, 0); __syncthreads();   // h = relu(u W1t + b)
        pass(Wl + 3 * 65536, bt2 + l * 256, 2); __syncthreads();   // t-path: v += t
    }

    // ---- epilogue: v -> out[:, 256+slice]
#pragma unroll
    for (int mt = 0; mt < 2; ++mt)
#pragma unroll
        for (int rt = 0; rt < 8; ++rt) {
            float* op = out + (size_t)(rowbase + rt * 16 + q) * 512 + 256 + wc + mt * 16 + g * 4;
            *(v4f*)op = v[mt][rt];
        }

    // evens: exact copy z -> out[:, :256]
    {
        const int r = tid >> 2, qt = tid & 3;
        const char* zr = (const char*)z + (size_t)(rowbase + r) * 2048 + qt * 512;
        float* op = out + (size_t)(rowbase + r) * 512 + qt * 64;
#pragma unroll
        for (int j = 0; j < 8; ++j) {
            v4f f0 = *(const v4f*)(zr + j * 64);
            v4f f1 = *(const v4f*)(zr + j * 64 + 16);
            v4f f2 = *(const v4f*)(zr + j * 64 + 32);
            v4f f3 = *(const v4f*)(zr + j * 64 + 48);
            v4f lo; lo.x = f0.x; lo.y = f0.z; lo.z = f1.x; lo.w = f1.z;
            v4f hi; hi.x = f2.x; hi.y = f2.z; hi.z = f3.x; hi.w = f3.z;
            *(v4f*)(op + j * 8)     = lo;
            *(v4f*)(op + j * 8 + 4) = hi;
        }
    }

    // logjac: sum over this wave's 32 cols (g-reduce), then over 8 waves via LDS
#pragma unroll
    for (int rt = 0; rt < 8; ++rt) {
        float s = lj[rt];
        s += __shfl_xor(s, 16);
        s += __shfl_xor(s, 32);
        lj[rt] = s;
    }
    float* ljb = (float*)(smem + LDS_LJ);
    if (g == 0) {
#pragma unroll
        for (int rt = 0; rt < 8; ++rt)
            ljb[wv * 128 + rt * 16 + q] = lj[rt];
    }
    __syncthreads();
    if (tid < 128) {
        float s = 0.0f;
#pragma unroll
        for (int w = 0; w < 8; ++w) s += ljb[w * 128 + tid];
        out[(size_t)NB * 512 + rowbase + tid] = s;
    }
}

// ---------------------------------------------------------------------------
extern "C" void kernel_launch(void* const* d_in, const int* in_sizes, int n_in,
                              void* d_out, int out_size, void* d_ws, size_t ws_size,
                              hipStream_t stream) {
    (void)in_sizes; (void)n_in; (void)out_size; (void)ws_size;
    const float* z   = (const float*)d_in[0];
    const float* Ws1 = (const float*)d_in[1];
    const float* bs1 = (const float*)d_in[2];
    const float* Ws2 = (const float*)d_in[3];
    const float* bs2 = (const float*)d_in[4];
    const float* Wt1 = (const float*)d_in[5];
    const float* bt1 = (const float*)d_in[6];
    const float* Wt2 = (const float*)d_in[7];
    const float* bt2 = (const float*)d_in[8];
    __hip_bfloat16* WT = (__hip_bfloat16*)d_ws;   // 4 MB bf16 transposed weights
    float* out = (float*)d_out;

    prep_weights<<<dim3(8192), dim3(256), 0, stream>>>(Ws1, Ws2, Wt1, Wt2, WT);

    hipFuncSetAttribute(reinterpret_cast<const void*>(realnvp_fused),
                        hipFuncAttributeMaxDynamicSharedMemorySize, LDS_SZ);
    realnvp_fused<<<dim3(512), dim3(512), LDS_SZ, stream>>>(z, bs1, bs2, bt1, bt2, WT, out);
}